// Round 5
// baseline (1587.832 us; speedup 1.0000x reference)
//
#include <hip/hip_runtime.h>

#define SEQ 365
#define BS  2048
#define HS  64
#define IND 32
#define XXC 5

typedef float f32x2 __attribute__((ext_vector_type(2)));

__device__ __forceinline__ f32x2 pkfma(f32x2 a, f32x2 b, f32x2 c) {
    return __builtin_elementwise_fma(a, b, c);
}

__device__ __forceinline__ float rcp_(float x) { return __builtin_amdgcn_rcpf(x); }
__device__ __forceinline__ float sig_(float x) { return rcp_(1.0f + __expf(-x)); }
__device__ __forceinline__ float tanh_(float x) { return 1.0f - 2.0f * rcp_(1.0f + __expf(2.0f * x)); }

// ---------------- Fused 3-wave gate-split TimeLSTM -----------------------
// R0-R4 model: (a) >~128 live floats/lane -> AGPR parking + copy per use
// (~2x VALU bloat, robust to asm/builtin/attributes); (b) materializing
// `pre` costs ~330us write + 574MB re-read. Fix both at once:
//   wave g owns gate g's columns only: Wh slice 32 f32x2 (64 regs) +
//   Wx slice 32 scalars ~= 96 weight regs -> fits, no copies.
//   x row is wave-uniform -> SGPRs via s_load (v_fma src0 = SGPR, free).
//   Gate pre-activations exchanged via parity ping-pong LDS, ONE barrier
//   per step. h needs no cross-wave ordering: every wave writes a complete
//   identical copy of h and reads back only its own (in-order DS).
//   t1 (wave0) / t2 (wave1) shared through LDS slots 3/4.
//   Next step's x-part is computed AFTER the barrier (independent of h_t),
//   shortening the inter-barrier critical section.
__global__ __launch_bounds__(192, 1)
void tlstm_fused(const float* __restrict__ x_for_h,
                 const float* __restrict__ x_for_x,
                 const float* __restrict__ td_in,
                 const float* __restrict__ Wx,    // [32][192]
                 const float* __restrict__ Wxm,   // [5][128]
                 const float* __restrict__ Wh,    // [64][192]
                 const float* __restrict__ Wt1,   // [64]
                 const float* __restrict__ Wt,    // [128]
                 const float* __restrict__ bias,  // [320]
                 float* __restrict__ out)
{
    __shared__ __align__(8) float hb[2][HS];     // h ping-pong (3 identical copies written)
    __shared__ float gb[2][5][HS];               // [par][i,c,o,t1,t2][lane]
    const int tid = threadIdx.x;
    const int g   = tid >> 6;        // 0: i-gate, 1: c_app-gate, 2: o-gate
    const int j   = tid & 63;
    const int b   = blockIdx.x;
    const int col = g * 64 + j;

    // this wave's gate column of Wh: 32 f32x2 = 64 VGPRs
    f32x2 whp[32];
#pragma unroll
    for (int m = 0; m < 32; ++m)
        whp[m] = {Wh[(2 * m) * 192 + col], Wh[(2 * m + 1) * 192 + col]};
    // this wave's gate column of Wx: 32 VGPRs
    float wx[IND];
#pragma unroll
    for (int k = 0; k < IND; ++k)
        wx[k] = Wx[k * 192 + col];

    const float bg   = (g == 0) ? bias[j] : (g == 1) ? bias[192 + j] : bias[256 + j];
    const float wtB  = Wt[64 + j];             // g==2 only
    const float wt1j = fminf(Wt1[j], 0.0f);    // g==0 only
    const float wtA  = Wt[j];                  // g==1 only
    const float bm   = (g == 1) ? bias[128 + j] : bias[64 + j];
    float wm[XXC];                              // g==0: Wxm[:, :64]; g==1: Wxm[:, 64:]
#pragma unroll
    for (int k = 0; k < XXC; ++k)
        wm[k] = (g == 1) ? Wxm[k * 128 + 64 + j] : Wxm[k * 128 + j];

    const float* xhb = x_for_h + (size_t)b * SEQ * IND;   // wave-uniform -> s_load
    const float* xxb = x_for_x + (size_t)b * SEQ * XXC;   // wave-uniform
    const float* tdp = td_in + (size_t)b * SEQ;           // wave-uniform
    float* outp = out + (size_t)b * SEQ * HS + j;

    hb[0][j] = 0.0f;     // each wave writes its own complete copy; reads only its own
    float h = 0.0f, c = 0.0f;

    // x-part for t=0: bg + x_0 @ wx  (x in SGPRs, weights in VGPRs)
    float xp;
    {
        float x0 = bg, x1 = 0.0f;
#pragma unroll
        for (int k = 0; k < IND; k += 2) {
            x0 = fmaf(xhb[k],     wx[k],     x0);
            x1 = fmaf(xhb[k + 1], wx[k + 1], x1);
        }
        xp = x0 + x1;
    }

    for (int t = 0; t < SEQ; ++t) {
        const int par = t & 1, nxt = par ^ 1;
        const float td = tdp[t];

        // h-part: 32 uniform ds_read_b64 broadcasts + 32 pkfma, 2 chains
        const f32x2* hp = (const f32x2*)hb[par];
        f32x2 a0 = {0.0f, 0.0f}, a1 = {0.0f, 0.0f};
#pragma unroll
        for (int m = 0; m < 32; m += 2) {
            a0 = pkfma(hp[m],     whp[m],     a0);
            a1 = pkfma(hp[m + 1], whp[m + 1], a1);
        }
        float ag = xp + (a0.x + a0.y) + (a1.x + a1.y);
        if (g == 2) ag = fmaf(td, wtB, ag);     // o-gate's td term
        gb[par][g][j] = ag;

        if (g == 0) {          // t1, fully formed
            float am = bm;
            const float* xq = xxb + (size_t)t * XXC;
#pragma unroll
            for (int k = 0; k < XXC; ++k) am = fmaf(xq[k], wm[k], am);
            gb[par][3][j] = sig_(am + tanh_(td * wt1j));
        } else if (g == 1) {   // t2, fully formed
            float am = bm;
            const float* xq = xxb + (size_t)t * XXC;
#pragma unroll
            for (int k = 0; k < XXC; ++k) am = fmaf(xq[k], wm[k], am);
            gb[par][4][j] = sig_(am + tanh_(td * wtA));
        }

        __syncthreads();

        const float ai  = gb[par][0][j];
        const float acg = gb[par][1][j];
        const float aog = gb[par][2][j];
        const float t1  = gb[par][3][j];
        const float t2  = gb[par][4][j];

        const float i_t  = sig_(ai);
        const float capp = tanh_(acg);
        const float it1  = i_t * t1;
        const float ctl  = sig_(fmaf(it1, capp - c, c));           // sig(c + i*t1*(capp-c))
        const float cn   = sig_(fmaf(i_t, fmaf(t2, capp, -c), c)); // sig(c + i*(t2*capp-c))
        const float o_t  = sig_(aog);
        const float hn   = o_t + tanh_(ctl);

        hb[nxt][j] = hn;                 // complete identical copy per wave
        if (g == 2) outp[(size_t)t * HS] = hn;
        h = hn; c = cn;

        // next step's x-part: independent of h_t -> fills the post-barrier slot
        if (t + 1 < SEQ) {
            const float* xr = xhb + (size_t)(t + 1) * IND;
            float x0 = bg, x1 = 0.0f;
#pragma unroll
            for (int k = 0; k < IND; k += 2) {
                x0 = fmaf(xr[k],     wx[k],     x0);
                x1 = fmaf(xr[k + 1], wx[k + 1], x1);
            }
            xp = x0 + x1;
        }
    }

    if (g == 2) {
        float* hT = out + (size_t)BS * SEQ * HS;
        float* cT = hT + (size_t)BS * HS;
        hT[(size_t)b * HS + j] = h;
        cT[(size_t)b * HS + j] = c;
    }
}

extern "C" void kernel_launch(void* const* d_in, const int* in_sizes, int n_in,
                              void* d_out, int out_size, void* d_ws, size_t ws_size,
                              hipStream_t stream)
{
    const float* x_for_h = (const float*)d_in[0];
    const float* x_for_x = (const float*)d_in[1];
    const float* TimeDiff = (const float*)d_in[2];
    const float* weights_x = (const float*)d_in[3];
    const float* weights_x_maintained = (const float*)d_in[4];
    const float* weights_h = (const float*)d_in[5];
    const float* weights_t1 = (const float*)d_in[6];
    const float* weights_t = (const float*)d_in[7];
    const float* bias = (const float*)d_in[8];
    float* out = (float*)d_out;

    tlstm_fused<<<BS, 192, 0, stream>>>(x_for_h, x_for_x, TimeDiff,
                                        weights_x, weights_x_maintained, weights_h,
                                        weights_t1, weights_t, bias, out);
}